// Round 1
// 5683.285 us; speedup vs baseline: 1.0099x; 1.0099x over previous
//
#include <hip/hip_runtime.h>
#include <hip/hip_bf16.h>

// Problem constants
#define BATCH   64
#define SEQ     512
#define DMODEL  256
#define HIDDEN  512
#define G3      1536      // 3*HIDDEN
#define NBLK    128       // scan blocks; 512 hidden units / 128 = 4 units/block
#define UPB     4         // units per block
#define CPB     12        // Wh columns per block (3 gates * UPB)
#define CHUNK   128       // timesteps per scan chunk-kernel
#define NCHUNK  4         // SEQ / CHUNK
#define HSLOT   (HIDDEN * BATCH)   // floats per h slot (128 KB)

typedef unsigned long long u64;
typedef unsigned int u32;

// ---------------------------------------------------------------------------
// Pack Wh slices: whp[blk][c][k] = Wh[k][ g*512 + blk*4 + u ]  (c = g*4+u)
// Contiguous in k -> wave-uniform weight reads scalarize (s_load). With no
// invalidation anywhere in the scan loop, each block's 24 KB slice stays
// L2-hot for the whole chunk.
// ---------------------------------------------------------------------------
__global__ __launch_bounds__(512) void prep_wh(const float* __restrict__ Wh,
                                               float* __restrict__ whp) {
    int t = blockIdx.x * 512 + threadIdx.x;      // 0 .. 786431
    int k   = t & 511;
    int cb  = t >> 9;          // blk*12 + c
    int c   = cb % 12;
    int blk = cb / 12;
    int u = c & 3, g = c >> 2;
    whp[t] = Wh[(long)k * G3 + g * HIDDEN + blk * UPB + u];
}

// ---------------------------------------------------------------------------
// Zero the 512 per-unit flags with agent-scope stores (the scan polls with
// L2-bypassing loads). Flags are monotonic global-step values across all
// 4 chunk kernels, so they are initialized exactly once per launch.
// ---------------------------------------------------------------------------
__global__ void init_flags(unsigned* flags) {
    __hip_atomic_store(&flags[threadIdx.x], 0u, __ATOMIC_RELAXED,
                       __HIP_MEMORY_SCOPE_AGENT);
}

// ---------------------------------------------------------------------------
// Chunked xg GEMM: xgC[col][lt][b] = emb[ids[b][s]] . Wx[:,col] + bx[col],
// s = chunk*CHUNK + lt. One 50 MB buffer reused per chunk; the consumer
// scan is a later kernel launch (entry-acquire) so reuse is coherent.
// ---------------------------------------------------------------------------
__global__ __launch_bounds__(256) void xg_gemm(const int* __restrict__ ids,
                                               const float* __restrict__ emb,
                                               const float* __restrict__ Wx,
                                               const float* __restrict__ bx,
                                               float* __restrict__ xgC,
                                               int chunk) {
    __shared__ float Es[64][68];   // Es[k][b], padded
    __shared__ float Ws[64][68];   // Ws[k][c], padded
    __shared__ int   sids[64];

    const int tid = threadIdx.x;
    const int nb = blockIdx.x;     // col tile 0..23
    const int lt = blockIdx.y;     // local timestep 0..127
    const int s  = chunk * CHUNK + lt;
    const int tn = tid & 15;
    const int tm = tid >> 4;

    if (tid < 64) sids[tid] = ids[tid * SEQ + s];   // id for batch=tid, step s
    __syncthreads();

    float acc[4][4];               // acc[i=col][j=b]
#pragma unroll
    for (int i = 0; i < 4; ++i)
#pragma unroll
        for (int j = 0; j < 4; ++j) acc[i][j] = 0.f;

    for (int kb = 0; kb < 256; kb += 64) {
#pragma unroll
        for (int p = 0; p < 4; ++p) {
            int b = p * 16 + tm;
            float4 av = *(const float4*)(emb + (long)sids[b] * DMODEL + kb + tn * 4);
            Es[tn * 4 + 0][b] = av.x;
            Es[tn * 4 + 1][b] = av.y;
            Es[tn * 4 + 2][b] = av.z;
            Es[tn * 4 + 3][b] = av.w;
            int krow = p * 16 + tm;
            float4 wv = *(const float4*)(Wx + (long)(kb + krow) * G3 + nb * 64 + tn * 4);
            *(float4*)&Ws[krow][tn * 4] = wv;
        }
        __syncthreads();
#pragma unroll
        for (int k = 0; k < 64; ++k) {
            float4 w4 = *(const float4*)&Ws[k][tm * 4];
            float4 e4 = *(const float4*)&Es[k][tn * 4];
            float ww[4] = {w4.x, w4.y, w4.z, w4.w};
            float ee[4] = {e4.x, e4.y, e4.z, e4.w};
#pragma unroll
            for (int i = 0; i < 4; ++i)
#pragma unroll
                for (int j = 0; j < 4; ++j)
                    acc[i][j] = fmaf(ww[i], ee[j], acc[i][j]);
        }
        __syncthreads();
    }

#pragma unroll
    for (int i = 0; i < 4; ++i) {
        int col = nb * 64 + tm * 4 + i;
        float bxi = bx[col];
        float4 o;
        o.x = acc[i][0] + bxi;
        o.y = acc[i][1] + bxi;
        o.z = acc[i][2] + bxi;
        o.w = acc[i][3] + bxi;
        *(float4*)(xgC + (long)col * (CHUNK * BATCH) + lt * 64 + tn * 4) = o;
    }
}

// ---------------------------------------------------------------------------
// GRU scan v9: collapsed handoff chain.
// v8's 10.4us/step was NOT bandwidth (HBM 1.2%) and NOT compute (VALU 1.4us)
// -- it was the serialized 4-barrier producer chain: syncA -> nonlin ->
// syncB -> LDS repack by different waves -> syncC(vmcnt drain of 8 waves)
// -> flag -> single-poller scan of 128 flags -> syncD -> then fetch.
// v9 collapses it:
//  * h slot layout [u][b] (unit-major): the wave that computes unit u's
//    nonlinearity stores its 64 batch lanes directly as ONE coalesced 256B
//    write-through store (4 full 64B lines). No LDS repack, no syncB.
//    hprev stays in a register of the producing wave.
//  * 512 per-UNIT flags: each producing wave drains only its OWN store
//    (per-wave s_waitcnt vmcnt(0)) then stores one flag. syncC/syncD gone.
//  * distributed detection: consumer wave wu polls exactly its 64 producer
//    flags (one coalesced 256B bypass load / iteration) and immediately
//    issues its own 64 plain h loads. Detect+fetch overlap across waves.
//  * double-buffered partial sums -> exactly ONE __syncthreads per step;
//    waves 4-7 run their next-step poll/load/FMA while waves 0-3 finish
//    reduce+nonlin+store+flag (s_setprio(1) keeps the producer tail ahead
//    of the co-resident FMA wave on the same SIMD).
// Correctness carried over from v8:
//  * fresh-slot rotation: every slot written once per chunk kernel; any
//    address is read only after flag >= t confirms its unique write, so
//    plain cached consumer loads are coherent (no stale L1/L2 copy can
//    exist: kernel-entry acquire invalidated everything, and first touch
//    is post-write). Cross-block skew <= 2 slots << 128 slots.
//  * flags monotonic across chunks (value = global step), init'd once.
//  * chunk boundary: exit-release + entry-acquire make slot 0 / flags
//    visible; lt==0 skips the poll entirely.
// Deadlock-free: flags only encode OTHER blocks' previous-step completion;
// the single intra-block barrier is per-step aligned across all 8 waves;
// 128 blocks co-resident (<=256 CUs, one kernel at a time).
// ---------------------------------------------------------------------------
__global__ __launch_bounds__(512, 2) void gru_scan(const float* __restrict__ whp,
                                                   const float* __restrict__ xgC,
                                                   const float* __restrict__ bh,
                                                   float* hist,
                                                   unsigned* flags,
                                                   int chunk) {
    const int tid = threadIdx.x;
    const int blk = blockIdx.x;
    const int b   = tid & 63;                                 // lane = batch
    const int wu  = __builtin_amdgcn_readfirstlane(tid >> 6); // wave 0..7

    __shared__ float part[2][8][CPB][64];   // 48 KB double-buffered partials

    const float* wb = whp + blk * (CPB * HIDDEN) + wu * 64;   // + c*512 + k
    const int base = chunk * CHUNK;

    // producer-wave state (waves 0-3 own unit jg = blk*4 + wu)
    int jg = 0;
    float bhr = 0.f, bhz = 0.f, bhn = 0.f, hprev = 0.f;
    const float* xr_p = nullptr; const float* xz_p = nullptr; const float* xn_p = nullptr;
    if (wu < 4) {
        jg  = blk * UPB + wu;
        bhr = bh[jg];
        bhz = bh[HIDDEN + jg];
        bhn = bh[2 * HIDDEN + jg];
        xr_p = xgC + (long)jg * (CHUNK * BATCH) + b;
        xz_p = xgC + (long)(HIDDEN + jg) * (CHUNK * BATCH) + b;
        xn_p = xgC + (long)(2 * HIDDEN + jg) * (CHUNK * BATCH) + b;
        // slot 0 holds h[base] (written by previous chunk kernel; fresh via
        // kernel-entry acquire). Chunk 0: h0 = 0.
        hprev = (chunk == 0) ? 0.f : hist[(long)jg * 64 + b];
    }

#pragma unroll 1
    for (int lt = 0; lt < CHUNK; ++lt) {
        const int t  = base + lt;
        const int pb = lt & 1;
        const float* hs = hist + (long)lt * HSLOT;                       // h[t]
        float*       hw = hist + (long)((lt + 1) & (CHUNK - 1)) * HSLOT; // h[t+1]

        // gate inputs: plain cached loads, issued before the poll so the
        // (possibly cold) fetch overlaps the wait.
        float xr = 0.f, xz = 0.f, xn = 0.f;
        if (wu < 4) {
            xr = xr_p[lt * 64];
            xz = xz_p[lt * 64];
            xn = xn_p[lt * 64];
        }

        float acc[CPB];
#pragma unroll
        for (int c = 0; c < CPB; ++c) acc[c] = 0.f;

        if (t > 0) {
            if (lt > 0) {
                // wave wu waits only for its 64 producers (units wu*64+b).
                const u32 tgt = (u32)t;
                for (;;) {
                    u32 f = __hip_atomic_load(&flags[wu * 64 + b], __ATOMIC_RELAXED,
                                              __HIP_MEMORY_SCOPE_AGENT);
                    if (__all((int)(f >= tgt))) break;
                    __builtin_amdgcn_s_sleep(1);
                }
            }
            // PLAIN pipelined bulk read of h[t][wu*64 .. wu*64+63][b]:
            // 64 coalesced dword loads (256B/instr, fresh addresses).
            const float* hq = hs + (long)wu * (64 * 64) + b;
            float hv[64];
#pragma unroll
            for (int i = 0; i < 64; ++i)
                hv[i] = hq[i * 64];

#pragma unroll
            for (int i = 0; i < 64; ++i) {
                const float hvv = hv[i];
#pragma unroll
                for (int c = 0; c < CPB; ++c)
                    acc[c] = fmaf(hvv, wb[c * HIDDEN + i], acc[c]);
            }
        }
        // else: h0 == 0 => partials are 0, hg = bh (analytic first step)

#pragma unroll
        for (int c = 0; c < CPB; ++c) part[pb][wu][c][b] = acc[c];
        __syncthreads();               // the ONLY barrier per step

        if (wu < 4) {
            __builtin_amdgcn_s_setprio(1);
            float hgr = bhr, hgz = bhz, hgn = bhn;
#pragma unroll
            for (int ww = 0; ww < 8; ++ww) {
                hgr += part[pb][ww][wu][b];
                hgz += part[pb][ww][4 + wu][b];
                hgn += part[pb][ww][8 + wu][b];
            }
            float r  = 1.f / (1.f + expf(-(xr + hgr)));
            float z  = 1.f / (1.f + expf(-(xz + hgz)));
            float nn = tanhf(xn + r * hgn);
            float hnew = (1.f - z) * nn + z * hprev;
            hprev = hnew;
            // direct coalesced write-through store of this wave's unit row
            __hip_atomic_store((u32*)hw + (long)jg * 64 + b, __float_as_uint(hnew),
                               __ATOMIC_RELAXED, __HIP_MEMORY_SCOPE_AGENT);
            // drain ONLY this wave's store, then publish the per-unit flag
            asm volatile("s_waitcnt vmcnt(0)" ::: "memory");
            if (b == 0)
                __hip_atomic_store(&flags[jg], (u32)(t + 1), __ATOMIC_RELAXED,
                                   __HIP_MEMORY_SCOPE_AGENT);
            __builtin_amdgcn_s_setprio(0);
        }
        // waves 4-7 proceed straight to step t+1's poll; their part writes
        // target buffer (pb^1), which waves 0-3 are not reading.
    }
}

// ---------------------------------------------------------------------------
// head: logits[b][n] = sum_k h[k][b] * Wo[k][n] + bo[n]
// h[512] sits in hist slot 0 (written by chunk 3's last step), [u][b] layout.
// ---------------------------------------------------------------------------
__global__ void head_kernel(const float* __restrict__ hist,
                            const float* __restrict__ Wo,
                            const float* __restrict__ bo,
                            float* __restrict__ out) {
    int tid = threadIdx.x;        // 128 threads
    int b = tid >> 1, n = tid & 1;
    float acc = bo[n];
#pragma unroll 8
    for (int k = 0; k < HIDDEN; ++k)
        acc = fmaf(hist[(long)k * 64 + b], Wo[k * 2 + n], acc);
    out[b * 2 + n] = acc;
}

// ---------------------------------------------------------------------------
extern "C" void kernel_launch(void* const* d_in, const int* in_sizes, int n_in,
                              void* d_out, int out_size, void* d_ws, size_t ws_size,
                              hipStream_t stream) {
    (void)in_sizes; (void)n_in; (void)out_size; (void)ws_size;
    const int*   ids = (const int*)  d_in[0];
    const float* emb = (const float*)d_in[1];
    const float* Wx  = (const float*)d_in[2];
    const float* Wh  = (const float*)d_in[3];
    const float* bx  = (const float*)d_in[4];
    const float* bh  = (const float*)d_in[5];
    const float* Wo  = (const float*)d_in[6];
    const float* bo  = (const float*)d_in[7];
    float* out = (float*)d_out;

    char* ws = (char*)d_ws;
    // ws layout: [flags 2KB][hist 16MB][whp 3MB][xgC 50.3MB]  (~70 MB total)
    // hist needs NO init: every slot is written before it is read in every
    // kernel that reads it (chunk0/lt0 skips the read analytically).
    unsigned* flags = (unsigned*)ws;
    float* hist = (float*)(ws + 2048);
    float* whp  = (float*)(ws + 2048 + (size_t)CHUNK * HSLOT * 4);
    float* xgC  = (float*)(ws + 2048 + (size_t)CHUNK * HSLOT * 4
                           + (size_t)NBLK * CPB * HIDDEN * 4);

    init_flags<<<dim3(1), dim3(512), 0, stream>>>(flags);
    prep_wh<<<dim3(1536), dim3(512), 0, stream>>>(Wh, whp);
    for (int c = 0; c < NCHUNK; ++c) {
        xg_gemm<<<dim3(24, CHUNK), dim3(256), 0, stream>>>(ids, emb, Wx, bx, xgC, c);
        gru_scan<<<dim3(NBLK), dim3(512), 0, stream>>>(whp, xgC, bh, hist, flags, c);
    }
    head_kernel<<<dim3(1), dim3(128), 0, stream>>>(hist, Wo, bo, out);
}

// Round 2
// 4971.782 us; speedup vs baseline: 1.1544x; 1.1431x over previous
//
#include <hip/hip_runtime.h>
#include <hip/hip_bf16.h>

// Problem constants
#define BATCH   64
#define SEQ     512
#define DMODEL  256
#define HIDDEN  512
#define G3      1536      // 3*HIDDEN
#define NBLK    128       // scan blocks; 512 hidden units / 128 = 4 units/block
#define UPB     4         // units per block
#define CPB     12        // Wh columns per block (3 gates * UPB)
#define CHUNK   128       // timesteps per scan chunk-kernel
#define NCHUNK  4         // SEQ / CHUNK
#define HSLOT   (HIDDEN * BATCH)   // floats per h slot (128 KB)

// Sentinel: negative quiet NaN bit pattern. Real h = (1-z)*n + z*h_prev with
// n in (-1,1), z in (0,1), h0=0  =>  h strictly in (-1,1), never NaN/inf.
#define SENT32  0xFFC00000u
#define SENT64  0xFFC00000FFC00000ULL

typedef unsigned long long u64;
typedef unsigned int u32;

// ---------------------------------------------------------------------------
// Pack Wh slices: whp[blk][c][k] = Wh[k][ g*512 + blk*4 + u ]  (c = g*4+u)
// Contiguous in k -> wave-uniform weight reads scalarize (s_load). With no
// invalidation anywhere in the scan loop, each block's 24 KB slice stays
// L2-hot for the whole chunk.
// ---------------------------------------------------------------------------
__global__ __launch_bounds__(512) void prep_wh(const float* __restrict__ Wh,
                                               float* __restrict__ whp) {
    int t = blockIdx.x * 512 + threadIdx.x;      // 0 .. 786431
    int k   = t & 511;
    int cb  = t >> 9;          // blk*12 + c
    int c   = cb % 12;
    int blk = cb / 12;
    int u = c & 3, g = c >> 2;
    whp[t] = Wh[(long)k * G3 + g * HIDDEN + blk * UPB + u];
}

// ---------------------------------------------------------------------------
// Sentinel-fill h-history slots 1..127 (slot 0 carries h[base] across the
// chunk boundary and is never polled before being valid). Agent-scope
// write-through stores so the next scan kernel's L2-bypassing polls see
// sentinel, not a stale cached line. 127 slots * 16384 u64 = 2,080,768 u64.
// ---------------------------------------------------------------------------
__global__ __launch_bounds__(256) void hist_clear(float* hist) {
    long i = (long)blockIdx.x * 256 + threadIdx.x;
    __hip_atomic_store((u64*)(hist + HSLOT) + i, SENT64,
                       __ATOMIC_RELAXED, __HIP_MEMORY_SCOPE_AGENT);
}

// ---------------------------------------------------------------------------
// Chunked xg GEMM: xgC[col][lt][b] = emb[ids[b][s]] . Wx[:,col] + bx[col],
// s = chunk*CHUNK + lt. One 50 MB buffer reused per chunk; the consumer
// scan is a later kernel launch (entry-acquire) so reuse is coherent.
// ---------------------------------------------------------------------------
__global__ __launch_bounds__(256) void xg_gemm(const int* __restrict__ ids,
                                               const float* __restrict__ emb,
                                               const float* __restrict__ Wx,
                                               const float* __restrict__ bx,
                                               float* __restrict__ xgC,
                                               int chunk) {
    __shared__ float Es[64][68];   // Es[k][b], padded
    __shared__ float Ws[64][68];   // Ws[k][c], padded
    __shared__ int   sids[64];

    const int tid = threadIdx.x;
    const int nb = blockIdx.x;     // col tile 0..23
    const int lt = blockIdx.y;     // local timestep 0..127
    const int s  = chunk * CHUNK + lt;
    const int tn = tid & 15;
    const int tm = tid >> 4;

    if (tid < 64) sids[tid] = ids[tid * SEQ + s];   // id for batch=tid, step s
    __syncthreads();

    float acc[4][4];               // acc[i=col][j=b]
#pragma unroll
    for (int i = 0; i < 4; ++i)
#pragma unroll
        for (int j = 0; j < 4; ++j) acc[i][j] = 0.f;

    for (int kb = 0; kb < 256; kb += 64) {
#pragma unroll
        for (int p = 0; p < 4; ++p) {
            int b = p * 16 + tm;
            float4 av = *(const float4*)(emb + (long)sids[b] * DMODEL + kb + tn * 4);
            Es[tn * 4 + 0][b] = av.x;
            Es[tn * 4 + 1][b] = av.y;
            Es[tn * 4 + 2][b] = av.z;
            Es[tn * 4 + 3][b] = av.w;
            int krow = p * 16 + tm;
            float4 wv = *(const float4*)(Wx + (long)(kb + krow) * G3 + nb * 64 + tn * 4);
            *(float4*)&Ws[krow][tn * 4] = wv;
        }
        __syncthreads();
#pragma unroll
        for (int k = 0; k < 64; ++k) {
            float4 w4 = *(const float4*)&Ws[k][tm * 4];
            float4 e4 = *(const float4*)&Es[k][tn * 4];
            float ww[4] = {w4.x, w4.y, w4.z, w4.w};
            float ee[4] = {e4.x, e4.y, e4.z, e4.w};
#pragma unroll
            for (int i = 0; i < 4; ++i)
#pragma unroll
                for (int j = 0; j < 4; ++j)
                    acc[i][j] = fmaf(ww[i], ee[j], acc[i][j]);
        }
        __syncthreads();
    }

#pragma unroll
    for (int i = 0; i < 4; ++i) {
        int col = nb * 64 + tm * 4 + i;
        float bxi = bx[col];
        float4 o;
        o.x = acc[i][0] + bxi;
        o.y = acc[i][1] + bxi;
        o.z = acc[i][2] + bxi;
        o.w = acc[i][3] + bxi;
        *(float4*)(xgC + (long)col * (CHUNK * BATCH) + lt * 64 + tn * 4) = o;
    }
}

// ---------------------------------------------------------------------------
// GRU scan v10: the data IS the flag.
// v8/v9 both sat at ~10.1us/step despite removing 3 of 4 barriers -> the
// shared cost was the handoff protocol: store -> vmcnt(0) drain -> flag
// store -> flag visibility round trip -> poll detect -> THEN a 64-load h
// fetch that the compiler fuses into the FMA loop in small groups (v9
// VGPR=52 proves hv[64] never lived in registers), each group paying a
// fresh-address latency round trip. ~4-5 serialized coherence-point trips.
// v10 collapses them into ONE:
//  * h slots 1..127 are pre-filled with a NaN sentinel (0xFFC00000) by a
//    clear kernel before each chunk. Real h is strictly in (-1,1): no
//    false positive possible.
//  * producer: computes h, issues ONE agent-scope write-through store.
//    No drain, no flag, nothing else.
//  * consumer wave: polls the h DATA itself -- 64 agent-scope (L1/L2-
//    bypassing) dword loads per iteration + non-sentinel check. The
//    validity check forces all 64 values live in VGPRs, so the loads
//    issue fully parallel (one round trip), and on detection the values
//    are ALREADY in registers -- the separate fetch stream is gone.
// Correctness:
//  * 4B stores are atomic: a poll sees either sentinel or the final value.
//  * skew bound: a block cannot pass step t's poll until every block
//    finished step t-1  =>  max inter-block skew = 1 step << 128-slot
//    reuse distance. Slot lt is sentinel until its unique in-kernel write.
//  * agent-scope loads provably observe remote write-through stores on
//    this part (v8/v9's flag polling worked); clears use the same scope.
//  * chunk carry: slot 0 is never cleared, written by prev chunk's last
//    step, read at lt=0 (poll exits on first iteration) and as hprev.
//    Chunk 0 skips step 0 analytically (h0 = 0).
// Deadlock-free: 128 blocks co-resident (<=256 CUs, one kernel at a time);
// forward progress by induction on t.
// ---------------------------------------------------------------------------
__global__ __launch_bounds__(512, 2) void gru_scan(const float* __restrict__ whp,
                                                   const float* __restrict__ xgC,
                                                   const float* __restrict__ bh,
                                                   float* hist,
                                                   int chunk) {
    const int tid = threadIdx.x;
    const int blk = blockIdx.x;
    const int b   = tid & 63;                                 // lane = batch
    const int wu  = __builtin_amdgcn_readfirstlane(tid >> 6); // wave 0..7

    __shared__ float part[2][8][CPB][64];   // 48 KB double-buffered partials

    const float* wb = whp + blk * (CPB * HIDDEN) + wu * 64;   // + c*512 + k
    const int base = chunk * CHUNK;

    // producer-wave state (waves 0-3 own unit jg = blk*4 + wu)
    int jg = 0;
    float bhr = 0.f, bhz = 0.f, bhn = 0.f, hprev = 0.f;
    const float* xr_p = nullptr; const float* xz_p = nullptr; const float* xn_p = nullptr;
    if (wu < 4) {
        jg  = blk * UPB + wu;
        bhr = bh[jg];
        bhz = bh[HIDDEN + jg];
        bhn = bh[2 * HIDDEN + jg];
        xr_p = xgC + (long)jg * (CHUNK * BATCH) + b;
        xz_p = xgC + (long)(HIDDEN + jg) * (CHUNK * BATCH) + b;
        xn_p = xgC + (long)(2 * HIDDEN + jg) * (CHUNK * BATCH) + b;
        // slot 0 holds h[base] (written by previous chunk kernel; fresh via
        // kernel-entry acquire). Chunk 0: h0 = 0.
        hprev = (chunk == 0) ? 0.f : hist[(long)jg * 64 + b];
    }

#pragma unroll 1
    for (int lt = 0; lt < CHUNK; ++lt) {
        const int t  = base + lt;
        const int pb = lt & 1;
        // this wave's 64 source units of h[t]: units wu*64 .. wu*64+63, batch b
        const u32* hq = (const u32*)(hist + (long)lt * HSLOT) + wu * (64 * 64) + b;
        float*     hw = hist + (long)((lt + 1) & (CHUNK - 1)) * HSLOT;   // h[t+1]

        // gate inputs: plain cached loads, issued before the poll so the
        // (possibly cold) fetch overlaps the wait.
        float xr = 0.f, xz = 0.f, xn = 0.f;
        if (wu < 4) {
            xr = xr_p[lt * 64];
            xz = xz_p[lt * 64];
            xn = xn_p[lt * 64];
        }

        float acc[CPB];
#pragma unroll
        for (int c = 0; c < CPB; ++c) acc[c] = 0.f;

        if (t > 0) {
            // poll the data: 64 parallel bypass loads + sentinel check.
            float hv[64];
            for (;;) {
                int valid = 1;
#pragma unroll
                for (int i = 0; i < 64; ++i) {
                    u32 w = __hip_atomic_load(hq + i * 64, __ATOMIC_RELAXED,
                                              __HIP_MEMORY_SCOPE_AGENT);
                    hv[i] = __uint_as_float(w);
                    valid &= (w != SENT32);
                }
                if (__all(valid)) break;
                // no sleep: each iteration self-throttles on memory latency
            }
#pragma unroll
            for (int i = 0; i < 64; ++i) {
                const float hvv = hv[i];
#pragma unroll
                for (int c = 0; c < CPB; ++c)
                    acc[c] = fmaf(hvv, wb[c * HIDDEN + i], acc[c]);
            }
        }
        // else: h0 == 0 => partials are 0, hg = bh (analytic first step)

#pragma unroll
        for (int c = 0; c < CPB; ++c) part[pb][wu][c][b] = acc[c];
        __syncthreads();               // the ONLY barrier per step

        if (wu < 4) {
            __builtin_amdgcn_s_setprio(1);
            float hgr = bhr, hgz = bhz, hgn = bhn;
#pragma unroll
            for (int ww = 0; ww < 8; ++ww) {
                hgr += part[pb][ww][wu][b];
                hgz += part[pb][ww][4 + wu][b];
                hgn += part[pb][ww][8 + wu][b];
            }
            float r  = 1.f / (1.f + expf(-(xr + hgr)));
            float z  = 1.f / (1.f + expf(-(xz + hgz)));
            float nn = tanhf(xn + r * hgn);
            float hnew = (1.f - z) * nn + z * hprev;
            hprev = hnew;
            // publish: ONE write-through store; consumers validate the data.
            __hip_atomic_store((u32*)hw + (long)jg * 64 + b, __float_as_uint(hnew),
                               __ATOMIC_RELAXED, __HIP_MEMORY_SCOPE_AGENT);
            __builtin_amdgcn_s_setprio(0);
        }
        // waves 4-7 proceed straight to step t+1's poll; their part writes
        // target buffer (pb^1), which waves 0-3 are not reading.
    }
}

// ---------------------------------------------------------------------------
// head: logits[b][n] = sum_k h[k][b] * Wo[k][n] + bo[n]
// h[512] sits in hist slot 0 (written by chunk 3's last step), [u][b] layout.
// ---------------------------------------------------------------------------
__global__ void head_kernel(const float* __restrict__ hist,
                            const float* __restrict__ Wo,
                            const float* __restrict__ bo,
                            float* __restrict__ out) {
    int tid = threadIdx.x;        // 128 threads
    int b = tid >> 1, n = tid & 1;
    float acc = bo[n];
#pragma unroll 8
    for (int k = 0; k < HIDDEN; ++k)
        acc = fmaf(hist[(long)k * 64 + b], Wo[k * 2 + n], acc);
    out[b * 2 + n] = acc;
}

// ---------------------------------------------------------------------------
extern "C" void kernel_launch(void* const* d_in, const int* in_sizes, int n_in,
                              void* d_out, int out_size, void* d_ws, size_t ws_size,
                              hipStream_t stream) {
    (void)in_sizes; (void)n_in; (void)out_size; (void)ws_size;
    const int*   ids = (const int*)  d_in[0];
    const float* emb = (const float*)d_in[1];
    const float* Wx  = (const float*)d_in[2];
    const float* Wh  = (const float*)d_in[3];
    const float* bx  = (const float*)d_in[4];
    const float* bh  = (const float*)d_in[5];
    const float* Wo  = (const float*)d_in[6];
    const float* bo  = (const float*)d_in[7];
    float* out = (float*)d_out;

    char* ws = (char*)d_ws;
    // ws layout: [hist 16MB][whp 3MB][xgC 50.3MB]  (~70 MB total)
    // hist slots 1..127 are sentinel-cleared before each chunk; slot 0 is
    // the cross-chunk carry (written before read in every kernel).
    float* hist = (float*)ws;
    float* whp  = (float*)(ws + (size_t)CHUNK * HSLOT * 4);
    float* xgC  = (float*)(ws + (size_t)CHUNK * HSLOT * 4
                           + (size_t)NBLK * CPB * HIDDEN * 4);

    prep_wh<<<dim3(1536), dim3(512), 0, stream>>>(Wh, whp);
    for (int c = 0; c < NCHUNK; ++c) {
        hist_clear<<<dim3(8128), dim3(256), 0, stream>>>(hist);
        xg_gemm<<<dim3(24, CHUNK), dim3(256), 0, stream>>>(ids, emb, Wx, bx, xgC, c);
        gru_scan<<<dim3(NBLK), dim3(512), 0, stream>>>(whp, xgC, bh, hist, c);
    }
    head_kernel<<<dim3(1), dim3(128), 0, stream>>>(hist, Wo, bo, out);
}